// Round 3
// baseline (1214.155 us; speedup 1.0000x reference)
//
#include <hip/hip_runtime.h>
#include <hip/hip_bf16.h>
#include <stdint.h>

#define TOKENS 8192
#define DIM 2048
#define EXPERTS 64
#define CAP 256
#define COMB_ELEMS ((size_t)TOKENS * EXPERTS * CAP)  // 134217728
#define OUT_ELEMS (1 + 2 * COMB_ELEMS)               // 268435457

// ---------------- threefry2x32 (exact JAX semantics) ----------------
__device__ __forceinline__ void tf_round(uint32_t& a, uint32_t& b, int r) {
  a += b;
  b = (b << r) | (b >> (32 - r));
  b ^= a;
}

__device__ __forceinline__ void threefry2x32(uint32_t k0, uint32_t k1,
                                             uint32_t x0, uint32_t x1,
                                             uint32_t& o0, uint32_t& o1) {
  const uint32_t ks0 = k0, ks1 = k1, ks2 = k0 ^ k1 ^ 0x1BD11BDAu;
  x0 += ks0; x1 += ks1;
  tf_round(x0, x1, 13); tf_round(x0, x1, 15); tf_round(x0, x1, 26); tf_round(x0, x1, 6);
  x0 += ks1; x1 += ks2 + 1u;
  tf_round(x0, x1, 17); tf_round(x0, x1, 29); tf_round(x0, x1, 16); tf_round(x0, x1, 24);
  x0 += ks2; x1 += ks0 + 2u;
  tf_round(x0, x1, 13); tf_round(x0, x1, 15); tf_round(x0, x1, 26); tf_round(x0, x1, 6);
  x0 += ks0; x1 += ks1 + 3u;
  tf_round(x0, x1, 17); tf_round(x0, x1, 29); tf_round(x0, x1, 16); tf_round(x0, x1, 24);
  x0 += ks1; x1 += ks2 + 4u;
  tf_round(x0, x1, 13); tf_round(x0, x1, 15); tf_round(x0, x1, 26); tf_round(x0, x1, 6);
  x0 += ks2; x1 += ks0 + 5u;
  o0 = x0; o1 = x1;
}

// ---------------- K0: bulk-zero the 1.074 GB output (replaces hipMemsetAsync) ----
__global__ __launch_bounds__(256) void k_zero(float* __restrict__ out) {
  const size_t n4 = OUT_ELEMS / 4;  // 67108864 float4s cover [0, 268435456)
  float4* o4 = reinterpret_cast<float4*>(out);
  size_t i = (size_t)blockIdx.x * blockDim.x + threadIdx.x;
  const size_t stride = (size_t)gridDim.x * blockDim.x;
  const float4 z = make_float4(0.f, 0.f, 0.f, 0.f);
  for (; i < n4; i += stride) o4[i] = z;
  if (blockIdx.x == 0 && threadIdx.x == 0) out[2 * COMB_ELEMS] = 0.f;  // tail elem
}

// ---------------- K1: logits = x @ wg^T  (fp32 vector GEMM) ----------------
// 256 blocks (32 tokens each) x 256 threads; tile 32x64, BK=32.
// wg staged TRANSPOSED in LDS ([k][expert], 256B rows) -> inner loop reads the
// 4-expert B-fragment with one conflict-free ds_read_b128.
__global__ __launch_bounds__(256) void k_logits(const float* __restrict__ x,
                                                const float* __restrict__ wg,
                                                float* __restrict__ logits) {
  __shared__ float xs[32][33];   // [token][k], pad 33: stores/reads 2-way max
  __shared__ float wt[32][64];   // [k][expert] transposed; rows = 256 B
  const int tid = threadIdx.x;
  const int tok0 = blockIdx.x * 32;
  const int e0 = (tid & 15) * 4;       // 4 experts per thread
  const int t0 = (tid >> 4) * 2;       // 2 tokens per thread

  const int xr = tid >> 3;             // 0..31 token row
  const int xc = (tid & 7) << 2;       // float4 col
  const int wr = tid >> 2;             // 0..63 expert row
  const int wc = (tid & 3) << 3;       // k col (2 float4s)

  const float* xp = x + (size_t)(tok0 + xr) * DIM + xc;
  const float* wp = wg + (size_t)wr * DIM + wc;

  float4 xv  = *reinterpret_cast<const float4*>(xp);
  float4 wv0 = *reinterpret_cast<const float4*>(wp);
  float4 wv1 = *reinterpret_cast<const float4*>(wp + 4);

  float acc[2][4] = {{0.f, 0.f, 0.f, 0.f}, {0.f, 0.f, 0.f, 0.f}};

  for (int k0 = 0; k0 < DIM; k0 += 32) {
    *reinterpret_cast<float4*>(&xs[xr][xc]) = xv;
    wt[wc + 0][wr] = wv0.x; wt[wc + 1][wr] = wv0.y;
    wt[wc + 2][wr] = wv0.z; wt[wc + 3][wr] = wv0.w;
    wt[wc + 4][wr] = wv1.x; wt[wc + 5][wr] = wv1.y;
    wt[wc + 6][wr] = wv1.z; wt[wc + 7][wr] = wv1.w;
    __syncthreads();
    if (k0 + 32 < DIM) {  // register prefetch of next tile overlaps compute
      xv  = *reinterpret_cast<const float4*>(xp + k0 + 32);
      wv0 = *reinterpret_cast<const float4*>(wp + k0 + 32);
      wv1 = *reinterpret_cast<const float4*>(wp + k0 + 36);
    }
#pragma unroll
    for (int kk = 0; kk < 32; ++kk) {
      const float4 b = *reinterpret_cast<const float4*>(&wt[kk][e0]);  // b128
      const float a0 = xs[t0][kk];
      const float a1 = xs[t0 + 1][kk];
      acc[0][0] = fmaf(a0, b.x, acc[0][0]);
      acc[0][1] = fmaf(a0, b.y, acc[0][1]);
      acc[0][2] = fmaf(a0, b.z, acc[0][2]);
      acc[0][3] = fmaf(a0, b.w, acc[0][3]);
      acc[1][0] = fmaf(a1, b.x, acc[1][0]);
      acc[1][1] = fmaf(a1, b.y, acc[1][1]);
      acc[1][2] = fmaf(a1, b.z, acc[1][2]);
      acc[1][3] = fmaf(a1, b.w, acc[1][3]);
    }
    __syncthreads();
  }
#pragma unroll
  for (int i = 0; i < 2; ++i) {
    float4 r = make_float4(acc[i][0], acc[i][1], acc[i][2], acc[i][3]);
    *reinterpret_cast<float4*>(&logits[(size_t)(tok0 + t0 + i) * EXPERTS + e0]) = r;
  }
}

// ---------------- K2: softmax + argmax1 + gumbel + argmax2 ----------------
__global__ __launch_bounds__(256) void k_gate(const float* __restrict__ logits,
    float* __restrict__ gates, int* __restrict__ e1, int* __restrict__ e2,
    float* __restrict__ g1, float* __restrict__ g2) {
  const int lane = threadIdx.x & 63;
  const int t = blockIdx.x * 4 + (threadIdx.x >> 6);
  const float logit = logits[(size_t)t * EXPERTS + lane];

  float m = logit;
#pragma unroll
  for (int off = 32; off > 0; off >>= 1) m = fmaxf(m, __shfl_xor(m, off));
  const float ex = expf(logit - m);
  float s = ex;
#pragma unroll
  for (int off = 32; off > 0; off >>= 1) s += __shfl_xor(s, off);
  const float gate = ex / s;
  gates[(size_t)t * EXPERTS + lane] = gate;

  float v1 = logit; int i1 = lane;
#pragma unroll
  for (int off = 32; off > 0; off >>= 1) {
    const float ov = __shfl_xor(v1, off);
    const int oi = __shfl_xor(i1, off);
    if (ov > v1 || (ov == v1 && oi < i1)) { v1 = ov; i1 = oi; }
  }

  // gumbel(key=42), jax_threefry_partitionable: counter=(0,i), bits = o0^o1
  const uint32_t i_flat = (uint32_t)t * 64u + (uint32_t)lane;
  uint32_t b0, b1;
  threefry2x32(0u, 42u, 0u, i_flat, b0, b1);
  const uint32_t bits = b0 ^ b1;
  float u = __uint_as_float((bits >> 9) | 0x3f800000u) - 1.0f;
  u += 1.17549435e-38f;
  const float gum = -logf(-logf(u));
  const float noisy = (lane == i1) ? -__builtin_inff() : (logit + gum);

  float v2 = noisy; int i2 = lane;
#pragma unroll
  for (int off = 32; off > 0; off >>= 1) {
    const float ov = __shfl_xor(v2, off);
    const int oi = __shfl_xor(i2, off);
    if (ov > v2 || (ov == v2 && oi < i2)) { v2 = ov; i2 = oi; }
  }

  const float gate1 = __shfl(gate, i1);
  const float gate2 = __shfl(gate, i2);
  if (lane == 0) { e1[t] = i1; e2[t] = i2; g1[t] = gate1; g2[t] = gate2; }
}

// ---------------- K3: per-expert prefix ranks + counts + gate col-sums ------
__global__ __launch_bounds__(256) void k_scan(const int* __restrict__ e1,
    const int* __restrict__ e2, const float* __restrict__ gates,
    int* __restrict__ loc1, int* __restrict__ loc2,
    int* __restrict__ counts1, float* __restrict__ gsum) {
  const int e = blockIdx.x;
  const int tid = threadIdx.x;
  const int lane = tid & 63;
  const int w = tid >> 6;
  __shared__ int wt4[4];
  __shared__ int carry;
  __shared__ float gw[4];
  if (tid == 0) carry = 0;

  float gs = 0.f;
  for (int base = 0; base < TOKENS; base += 256) {
    const int t = base + tid;
    const int p = (e1[t] == e) ? 1 : 0;
    gs += gates[(size_t)t * EXPERTS + e];
    const uint64_t mask = __ballot(p);
    const int rk = __popcll(mask & ((1ull << lane) - 1ull));
    if (lane == 0) wt4[w] = __popcll(mask);
    __syncthreads();
    int pre = carry;
#pragma unroll
    for (int i = 0; i < 4; ++i)
      if (i < w) pre += wt4[i];
    if (p) loc1[t] = pre + rk;
    const int tot = wt4[0] + wt4[1] + wt4[2] + wt4[3];
    __syncthreads();
    if (tid == 0) carry += tot;
  }
  __syncthreads();
  if (tid == 0) counts1[e] = carry;
  for (int base = 0; base < TOKENS; base += 256) {
    const int t = base + tid;
    const int p = (e2[t] == e) ? 1 : 0;
    const uint64_t mask = __ballot(p);
    const int rk = __popcll(mask & ((1ull << lane) - 1ull));
    if (lane == 0) wt4[w] = __popcll(mask);
    __syncthreads();
    int pre = carry;
#pragma unroll
    for (int i = 0; i < 4; ++i)
      if (i < w) pre += wt4[i];
    if (p) loc2[t] = pre + rk;
    const int tot = wt4[0] + wt4[1] + wt4[2] + wt4[3];
    __syncthreads();
    if (tid == 0) carry += tot;
  }
#pragma unroll
  for (int off = 32; off > 0; off >>= 1) gs += __shfl_xor(gs, off);
  if (lane == 0) gw[w] = gs;
  __syncthreads();
  if (tid == 0) gsum[e] = gw[0] + gw[1] + gw[2] + gw[3];
}

// ---------------- K4: l_aux ----------------
__global__ void k_laux(const float* __restrict__ gsum, const int* __restrict__ counts1,
                       float* __restrict__ out) {
  const int lane = threadIdx.x;
  float v = gsum[lane] * (float)counts1[lane];
#pragma unroll
  for (int off = 32; off > 0; off >>= 1) v += __shfl_xor(v, off);
  if (lane == 0) out[0] = v * (1.0f / 1048576.0f);
}

// ---------------- K5: sparse scatter ----------------
__global__ __launch_bounds__(256) void k_scatter(const int* __restrict__ e1,
    const int* __restrict__ e2, const float* __restrict__ g1,
    const float* __restrict__ g2, const int* __restrict__ loc1,
    const int* __restrict__ loc2, float* __restrict__ out) {
  const int t = blockIdx.x * 256 + threadIdx.x;
  const int a = e1[t], b = e2[t];
  const int l1 = loc1[t], l2 = loc2[t];
  const bool k1 = l1 < CAP;
  const bool k2 = l2 < CAP;
  const float ga = k1 ? g1[t] : 0.f;
  const float gb = k2 ? g2[t] : 0.f;
  const float denom = fmaxf(ga + gb, 1.1920929e-07f);
  float* __restrict__ combine = out + 1;
  float* __restrict__ dispatch = out + 1 + COMB_ELEMS;
  if (k1) {
    const size_t idx = ((size_t)t * EXPERTS + a) * CAP + l1;
    combine[idx] = ga / denom;
    dispatch[idx] = 1.0f;
  }
  if (k2) {
    const size_t idx = ((size_t)t * EXPERTS + b) * CAP + l2;
    combine[idx] = gb / denom;
    dispatch[idx] = 1.0f;
  }
}

extern "C" void kernel_launch(void* const* d_in, const int* in_sizes, int n_in,
                              void* d_out, int out_size, void* d_ws, size_t ws_size,
                              hipStream_t stream) {
  const float* x = (const float*)d_in[0];
  const float* wg = (const float*)d_in[1];
  float* out = (float*)d_out;

  float* ws = (float*)d_ws;
  float* logits  = ws;                        // 524288 f32
  float* gates   = ws + 524288;               // 524288 f32
  int*   e1      = (int*)(ws + 1048576);      // 8192 i32
  int*   e2      = e1 + TOKENS;
  int*   loc1    = e2 + TOKENS;
  int*   loc2    = loc1 + TOKENS;
  int*   counts1 = loc2 + TOKENS;             // 64
  float* g1      = (float*)(counts1 + 64);
  float* g2      = g1 + TOKENS;
  float* gsum    = g2 + TOKENS;               // 64

  k_zero<<<2048, 256, 0, stream>>>(out);
  k_logits<<<TOKENS / 32, 256, 0, stream>>>(x, wg, logits);
  k_gate<<<TOKENS / 4, 256, 0, stream>>>(logits, gates, e1, e2, g1, g2);
  k_scan<<<EXPERTS, 256, 0, stream>>>(e1, e2, gates, loc1, loc2, counts1, gsum);
  k_laux<<<1, 64, 0, stream>>>(gsum, counts1, out);
  k_scatter<<<TOKENS / 256, 256, 0, stream>>>(e1, e2, g1, g2, loc1, loc2, out);
}

// Round 4
// 1142.557 us; speedup vs baseline: 1.0627x; 1.0627x over previous
//
#include <hip/hip_runtime.h>
#include <hip/hip_bf16.h>
#include <stdint.h>

#define TOKENS 8192
#define DIM 2048
#define EXPERTS 64
#define CAP 256
#define COMB_ELEMS ((size_t)TOKENS * EXPERTS * CAP)  // 134217728
#define OUT_ELEMS (1 + 2 * COMB_ELEMS)               // 268435457

#define GEMM_BLOCKS 256
#define ZERO_BLOCKS 2048

// ---------------- threefry2x32 (exact JAX semantics) ----------------
__device__ __forceinline__ void tf_round(uint32_t& a, uint32_t& b, int r) {
  a += b;
  b = (b << r) | (b >> (32 - r));
  b ^= a;
}

__device__ __forceinline__ void threefry2x32(uint32_t k0, uint32_t k1,
                                             uint32_t x0, uint32_t x1,
                                             uint32_t& o0, uint32_t& o1) {
  const uint32_t ks0 = k0, ks1 = k1, ks2 = k0 ^ k1 ^ 0x1BD11BDAu;
  x0 += ks0; x1 += ks1;
  tf_round(x0, x1, 13); tf_round(x0, x1, 15); tf_round(x0, x1, 26); tf_round(x0, x1, 6);
  x0 += ks1; x1 += ks2 + 1u;
  tf_round(x0, x1, 17); tf_round(x0, x1, 29); tf_round(x0, x1, 16); tf_round(x0, x1, 24);
  x0 += ks2; x1 += ks0 + 2u;
  tf_round(x0, x1, 13); tf_round(x0, x1, 15); tf_round(x0, x1, 26); tf_round(x0, x1, 6);
  x0 += ks0; x1 += ks1 + 3u;
  tf_round(x0, x1, 17); tf_round(x0, x1, 29); tf_round(x0, x1, 16); tf_round(x0, x1, 24);
  x0 += ks1; x1 += ks2 + 4u;
  tf_round(x0, x1, 13); tf_round(x0, x1, 15); tf_round(x0, x1, 26); tf_round(x0, x1, 6);
  x0 += ks2; x1 += ks0 + 5u;
  o0 = x0; o1 = x1;
}

// ---------------- K1: fused {GEMM+gate} (blocks 0..255) + {zero out} (256..2303)
// GEMM: tile 32 tokens x 64 experts, BK=32, wg staged transposed -> b128 reads.
// Gate epilogue runs on the block's score tile in LDS: softmax, argmax1,
// threefry-gumbel, argmax2, per-block gate column sums -> gpart[block][64].
__global__ __launch_bounds__(256) void k_fused(const float* __restrict__ x,
                                               const float* __restrict__ wg,
                                               float* __restrict__ out,
                                               int* __restrict__ e1, int* __restrict__ e2,
                                               float* __restrict__ g1, float* __restrict__ g2,
                                               float* __restrict__ gpart) {
  __shared__ float xs[32][33];     // [token][k]
  __shared__ float wt[32][64];     // [k][expert] transposed; reused as score[t][e]
  __shared__ float gpl[4][64];     // per-wave gate column partials

  const int tid = threadIdx.x;

  if (blockIdx.x >= GEMM_BLOCKS) {
    // ---- zero path: 2048 blocks cover 1.074 GB in float4s ----
    const size_t n4 = OUT_ELEMS / 4;  // 67108864
    float4* o4 = reinterpret_cast<float4*>(out);
    const int zb = blockIdx.x - GEMM_BLOCKS;
    size_t i = (size_t)zb * 256 + tid;
    const size_t stride = (size_t)ZERO_BLOCKS * 256;
    const float4 z = make_float4(0.f, 0.f, 0.f, 0.f);
    for (; i < n4; i += stride) o4[i] = z;
    if (zb == 0 && tid == 0) out[2 * COMB_ELEMS] = 0.f;  // tail element
    return;
  }

  // ---- GEMM path ----
  const int tok0 = blockIdx.x * 32;
  const int e0 = (tid & 15) * 4;       // 4 experts per thread
  const int t0 = (tid >> 4) * 2;       // 2 tokens per thread

  const int xr = tid >> 3;             // 0..31 token row
  const int xc = (tid & 7) << 2;       // float4 col
  const int wr = tid >> 2;             // 0..63 expert row
  const int wc = (tid & 3) << 3;       // k col (2 float4s)

  const float* xp = x + (size_t)(tok0 + xr) * DIM + xc;
  const float* wp = wg + (size_t)wr * DIM + wc;

  float4 xv  = *reinterpret_cast<const float4*>(xp);
  float4 wv0 = *reinterpret_cast<const float4*>(wp);
  float4 wv1 = *reinterpret_cast<const float4*>(wp + 4);

  float acc[2][4] = {{0.f, 0.f, 0.f, 0.f}, {0.f, 0.f, 0.f, 0.f}};

  for (int k0 = 0; k0 < DIM; k0 += 32) {
    *reinterpret_cast<float4*>(&xs[xr][xc]) = xv;
    wt[wc + 0][wr] = wv0.x; wt[wc + 1][wr] = wv0.y;
    wt[wc + 2][wr] = wv0.z; wt[wc + 3][wr] = wv0.w;
    wt[wc + 4][wr] = wv1.x; wt[wc + 5][wr] = wv1.y;
    wt[wc + 6][wr] = wv1.z; wt[wc + 7][wr] = wv1.w;
    __syncthreads();
    if (k0 + 32 < DIM) {  // register prefetch overlaps compute
      xv  = *reinterpret_cast<const float4*>(xp + k0 + 32);
      wv0 = *reinterpret_cast<const float4*>(wp + k0 + 32);
      wv1 = *reinterpret_cast<const float4*>(wp + k0 + 36);
    }
#pragma unroll
    for (int kk = 0; kk < 32; ++kk) {
      const float4 b = *reinterpret_cast<const float4*>(&wt[kk][e0]);
      const float a0 = xs[t0][kk];
      const float a1 = xs[t0 + 1][kk];
      acc[0][0] = fmaf(a0, b.x, acc[0][0]);
      acc[0][1] = fmaf(a0, b.y, acc[0][1]);
      acc[0][2] = fmaf(a0, b.z, acc[0][2]);
      acc[0][3] = fmaf(a0, b.w, acc[0][3]);
      acc[1][0] = fmaf(a1, b.x, acc[1][0]);
      acc[1][1] = fmaf(a1, b.y, acc[1][1]);
      acc[1][2] = fmaf(a1, b.z, acc[1][2]);
      acc[1][3] = fmaf(a1, b.w, acc[1][3]);
    }
    __syncthreads();
  }

  // scores -> LDS (reuse wt as score[token][expert])
#pragma unroll
  for (int i = 0; i < 2; ++i)
    *reinterpret_cast<float4*>(&wt[t0 + i][e0]) =
        make_float4(acc[i][0], acc[i][1], acc[i][2], acc[i][3]);
  __syncthreads();

  // ---- gate epilogue: wave w handles local tokens w*8 .. w*8+7 ----
  const int w = tid >> 6;
  const int lane = tid & 63;
  float colsum = 0.f;
  for (int lt = w * 8; lt < w * 8 + 8; ++lt) {
    const int t = tok0 + lt;
    const float logit = wt[lt][lane];

    float m = logit;
#pragma unroll
    for (int off = 32; off > 0; off >>= 1) m = fmaxf(m, __shfl_xor(m, off));
    const float ex = expf(logit - m);
    float s = ex;
#pragma unroll
    for (int off = 32; off > 0; off >>= 1) s += __shfl_xor(s, off);
    const float gate = ex / s;
    colsum += gate;

    float v1 = logit; int i1 = lane;
#pragma unroll
    for (int off = 32; off > 0; off >>= 1) {
      const float ov = __shfl_xor(v1, off);
      const int oi = __shfl_xor(i1, off);
      if (ov > v1 || (ov == v1 && oi < i1)) { v1 = ov; i1 = oi; }
    }

    // gumbel(key=42), jax_threefry_partitionable: counter=(0,i), bits=o0^o1
    const uint32_t i_flat = (uint32_t)t * 64u + (uint32_t)lane;
    uint32_t b0, b1;
    threefry2x32(0u, 42u, 0u, i_flat, b0, b1);
    const uint32_t bits = b0 ^ b1;
    float u = __uint_as_float((bits >> 9) | 0x3f800000u) - 1.0f;
    u += 1.17549435e-38f;
    const float gum = -logf(-logf(u));
    const float noisy = (lane == i1) ? -__builtin_inff() : (logit + gum);

    float v2 = noisy; int i2 = lane;
#pragma unroll
    for (int off = 32; off > 0; off >>= 1) {
      const float ov = __shfl_xor(v2, off);
      const int oi = __shfl_xor(i2, off);
      if (ov > v2 || (ov == v2 && oi < i2)) { v2 = ov; i2 = oi; }
    }

    const float gate1 = __shfl(gate, i1);
    const float gate2 = __shfl(gate, i2);
    if (lane == 0) { e1[t] = i1; e2[t] = i2; g1[t] = gate1; g2[t] = gate2; }
  }
  // block-level gate column partial sums (deterministic; reduced in k_scan)
  gpl[w][lane] = colsum;
  __syncthreads();
  if (w == 0)
    gpart[(size_t)blockIdx.x * 64 + lane] =
        (gpl[0][lane] + gpl[1][lane]) + (gpl[2][lane] + gpl[3][lane]);
}

// ---------------- K2: per-expert prefix ranks + counts + gsum reduce ----
__global__ __launch_bounds__(256) void k_scan(const int* __restrict__ e1,
    const int* __restrict__ e2, const float* __restrict__ gpart,
    int* __restrict__ loc1, int* __restrict__ loc2,
    int* __restrict__ counts1, float* __restrict__ gsum) {
  const int e = blockIdx.x;
  const int tid = threadIdx.x;
  const int lane = tid & 63;
  const int w = tid >> 6;
  __shared__ int wt4[4];
  __shared__ int carry;
  __shared__ float gw[4];
  if (tid == 0) carry = 0;

  // gsum[e] = sum_b gpart[b][e] (deterministic tree)
  float gp = gpart[(size_t)tid * 64 + e];
#pragma unroll
  for (int off = 32; off > 0; off >>= 1) gp += __shfl_xor(gp, off);
  if (lane == 0) gw[w] = gp;
  __syncthreads();
  if (tid == 0) gsum[e] = (gw[0] + gw[1]) + (gw[2] + gw[3]);

  for (int base = 0; base < TOKENS; base += 256) {
    const int t = base + tid;
    const int p = (e1[t] == e) ? 1 : 0;
    const uint64_t mask = __ballot(p);
    const int rk = __popcll(mask & ((1ull << lane) - 1ull));
    if (lane == 0) wt4[w] = __popcll(mask);
    __syncthreads();
    int pre = carry;
#pragma unroll
    for (int i = 0; i < 4; ++i)
      if (i < w) pre += wt4[i];
    if (p) loc1[t] = pre + rk;
    const int tot = wt4[0] + wt4[1] + wt4[2] + wt4[3];
    __syncthreads();
    if (tid == 0) carry += tot;
  }
  __syncthreads();
  if (tid == 0) counts1[e] = carry;  // pre-drop top-1 count (for l_aux, loc2 base)
  for (int base = 0; base < TOKENS; base += 256) {
    const int t = base + tid;
    const int p = (e2[t] == e) ? 1 : 0;
    const uint64_t mask = __ballot(p);
    const int rk = __popcll(mask & ((1ull << lane) - 1ull));
    if (lane == 0) wt4[w] = __popcll(mask);
    __syncthreads();
    int pre = carry;
#pragma unroll
    for (int i = 0; i < 4; ++i)
      if (i < w) pre += wt4[i];
    if (p) loc2[t] = pre + rk;
    const int tot = wt4[0] + wt4[1] + wt4[2] + wt4[3];
    __syncthreads();
    if (tid == 0) carry += tot;
  }
}

// ---------------- K3: sparse scatter + l_aux (block 0) ----------------
__global__ __launch_bounds__(256) void k_scatter(const int* __restrict__ e1,
    const int* __restrict__ e2, const float* __restrict__ g1,
    const float* __restrict__ g2, const int* __restrict__ loc1,
    const int* __restrict__ loc2, const float* __restrict__ gsum,
    const int* __restrict__ counts1, float* __restrict__ out) {
  const int tid = threadIdx.x;
  if (blockIdx.x == 0 && tid < 64) {  // l_aux on wave 0 of block 0
    float v = gsum[tid] * (float)counts1[tid];
#pragma unroll
    for (int off = 32; off > 0; off >>= 1) v += __shfl_xor(v, off);
    if (tid == 0) out[0] = v * (1.0f / 1048576.0f);
  }
  const int t = blockIdx.x * 256 + tid;
  const int a = e1[t], b = e2[t];
  const int l1 = loc1[t], l2 = loc2[t];
  const bool k1 = l1 < CAP;
  const bool k2 = l2 < CAP;
  const float ga = k1 ? g1[t] : 0.f;
  const float gb = k2 ? g2[t] : 0.f;
  const float denom = fmaxf(ga + gb, 1.1920929e-07f);
  float* __restrict__ combine = out + 1;
  float* __restrict__ dispatch = out + 1 + COMB_ELEMS;
  if (k1) {
    const size_t idx = ((size_t)t * EXPERTS + a) * CAP + l1;
    combine[idx] = ga / denom;
    dispatch[idx] = 1.0f;
  }
  if (k2) {
    const size_t idx = ((size_t)t * EXPERTS + b) * CAP + l2;
    combine[idx] = gb / denom;
    dispatch[idx] = 1.0f;
  }
}

extern "C" void kernel_launch(void* const* d_in, const int* in_sizes, int n_in,
                              void* d_out, int out_size, void* d_ws, size_t ws_size,
                              hipStream_t stream) {
  const float* x = (const float*)d_in[0];
  const float* wg = (const float*)d_in[1];
  float* out = (float*)d_out;

  int*   e1      = (int*)d_ws;                // 8192 i32
  int*   e2      = e1 + TOKENS;
  int*   loc1    = e2 + TOKENS;
  int*   loc2    = loc1 + TOKENS;
  int*   counts1 = loc2 + TOKENS;             // 64
  float* g1      = (float*)(counts1 + 64);    // 8192 f32
  float* g2      = g1 + TOKENS;
  float* gsum    = g2 + TOKENS;               // 64
  float* gpart   = gsum + 64;                 // 256*64 f32

  k_fused<<<GEMM_BLOCKS + ZERO_BLOCKS, 256, 0, stream>>>(x, wg, out, e1, e2, g1, g2, gpart);
  k_scan<<<EXPERTS, 256, 0, stream>>>(e1, e2, gpart, loc1, loc2, counts1, gsum);
  k_scatter<<<TOKENS / 256, 256, 0, stream>>>(e1, e2, g1, g2, loc1, loc2, gsum, counts1, out);
}